// Round 1
// baseline (27821.118 us; speedup 1.0000x reference)
//
#include <hip/hip_runtime.h>
#include <hip/hip_bf16.h>
#include <stdint.h>

#define HH 1024
#define BB 64
#define TT 1024

typedef __attribute__((ext_vector_type(8))) short short8;
typedef __attribute__((ext_vector_type(4))) float f32x4;

__device__ __forceinline__ unsigned short f2bf(float f) {
  union { float f; unsigned u; } v; v.f = f;
  unsigned r = v.u + 0x7fffu + ((v.u >> 16) & 1u);
  return (unsigned short)(r >> 16);
}

// Convert weights to bf16 (RNE) and fold the two biases together.
__global__ void prep_kernel(const float* __restrict__ Wih, const float* __restrict__ Whh,
                            const float* __restrict__ bih, const float* __restrict__ bhh,
                            unsigned short* __restrict__ wih_b, unsigned short* __restrict__ whh_b,
                            float* __restrict__ bias01) {
  int i = blockIdx.x * 256 + threadIdx.x;   // grid sized exactly 2*H*H
  wih_b[i] = f2bf(Wih[i]);
  whh_b[i] = f2bf(Whh[i]);
  if (i < 2 * HH) bias01[i] = bih[i] + bhh[i];
}

// Bulk GEMM: Gout[r, n] = sum_k A[r,k] * W[n,k] + bias[n].
// A is fp32 (converted on the fly) or bf16. M = 65536, N = K = 1024.
// 128x128 tile, BK=32, 4 waves each computing 64x64 (4x4 of 16x16x32 MFMA).
template<bool ABF16>
__global__ __launch_bounds__(256)
void gemm_bias(const void* __restrict__ Av, const unsigned short* __restrict__ Wb,
               const float* __restrict__ bias, float* __restrict__ Gout) {
  __shared__ unsigned short As[128 * 40];  // +8 bf16 pad: 80B stride -> 2-way bank alias (free)
  __shared__ unsigned short Bs[128 * 40];
  const int tn = blockIdx.x & 7;
  const int tm = blockIdx.x >> 3;
  const int tid = threadIdx.x;
  const int wid = tid >> 6, lane = tid & 63;
  const int wr = (wid >> 1) * 64, wc = (wid & 1) * 64;
  const int l15 = lane & 15, l4 = lane >> 4;
  f32x4 acc[4][4] = {};

  const float* Af = (const float*)Av;
  const unsigned short* Ab = (const unsigned short*)Av;
  const int sr = tid >> 2;          // 0..63
  const int sk = (tid & 3) * 8;     // 0,8,16,24

  for (int k0 = 0; k0 < HH; k0 += 32) {
    __syncthreads();
#pragma unroll
    for (int p = 0; p < 2; ++p) {
      const int row = p * 64 + sr;
      if (ABF16) {
        const unsigned short* src = Ab + (size_t)(tm * 128 + row) * HH + k0 + sk;
        *(short8*)&As[row * 40 + sk] = *(const short8*)src;
      } else {
        const float* src = Af + (size_t)(tm * 128 + row) * HH + k0 + sk;
        float4 x = *(const float4*)src;
        float4 y = *(const float4*)(src + 4);
        short8 v;
        v[0] = (short)f2bf(x.x); v[1] = (short)f2bf(x.y);
        v[2] = (short)f2bf(x.z); v[3] = (short)f2bf(x.w);
        v[4] = (short)f2bf(y.x); v[5] = (short)f2bf(y.y);
        v[6] = (short)f2bf(y.z); v[7] = (short)f2bf(y.w);
        *(short8*)&As[row * 40 + sk] = v;
      }
      const unsigned short* wsrc = Wb + (size_t)(tn * 128 + row) * HH + k0 + sk;
      *(short8*)&Bs[row * 40 + sk] = *(const short8*)wsrc;
    }
    __syncthreads();
    short8 a[4], b[4];
#pragma unroll
    for (int i = 0; i < 4; ++i) a[i] = *(short8*)&As[(wr + i * 16 + l15) * 40 + l4 * 8];
#pragma unroll
    for (int j = 0; j < 4; ++j) b[j] = *(short8*)&Bs[(wc + j * 16 + l15) * 40 + l4 * 8];
#pragma unroll
    for (int i = 0; i < 4; ++i)
#pragma unroll
      for (int j = 0; j < 4; ++j)
        acc[i][j] = __builtin_amdgcn_mfma_f32_16x16x32_bf16(a[i], b[j], acc[i][j], 0, 0, 0);
  }
#pragma unroll
  for (int j = 0; j < 4; ++j) {
    const int gc = tn * 128 + wc + j * 16 + l15;
    const float bv = bias[gc];
#pragma unroll
    for (int i = 0; i < 4; ++i) {
#pragma unroll
      for (int jj = 0; jj < 4; ++jj) {
        const int gr = tm * 128 + wr + i * 16 + l4 * 4 + jj;
        Gout[(size_t)gr * HH + gc] = acc[i][j][jj] + bv;
      }
    }
  }
}

// Persistent recurrent kernel (one layer). 64 WGs x 256 threads, cooperative.
// WG g owns output columns [g*16, g*16+16). Whh column-slice resident in LDS.
// Per step t: pre = G[:,t,cols] + h_{t-1} @ Whh_sliceT ; h = tanh(pre).
// Hand-rolled flag-array barrier with agent-scope release/acquire + threadfence.
__global__ __launch_bounds__(256)
void rec_layer(const float* G,                       // [B*T*H] pre-activations (no restrict: may alias outf)
               const unsigned short* __restrict__ Whh_b,  // [H][H] bf16
               unsigned short* __restrict__ ping,    // [2][B*H] bf16 recurrent state ping-pong
               unsigned short* __restrict__ h0strided, // layer0: [B*T*H] bf16 outputs, else null
               float* outf,                          // layer1: fp32 out (in-place over G), else null
               float* __restrict__ hT,               // [B*H] final hidden (fp32)
               unsigned int* flags) {                // 64 flags, 1KB apart
  const int g = blockIdx.x;
  const int tid = threadIdx.x, wid = tid >> 6, lane = tid & 63;
  const int l15 = lane & 15, kp = (lane >> 4) * 8;
  __shared__ unsigned short Wl[16 * 1032];  // 16 cols x 1024 k, stride 1032 (2-way bank alias only)

  for (int idx = tid; idx < 16 * 64; idx += 256) {
    const int j = idx >> 6, kseg = (idx & 63) * 16;
    const short8* src = (const short8*)&Whh_b[(size_t)(g * 16 + j) * HH + kseg];
    *(short8*)&Wl[j * 1032 + kseg] = src[0];
    *(short8*)&Wl[j * 1032 + kseg + 8] = src[1];
  }
  __syncthreads();

  const int col = g * 16 + l15;
  const unsigned short* brow = (const unsigned short*)&Wl[l15 * 1032 + kp];

  for (int t = 0; t < TT; ++t) {
    f32x4 acc0 = {}, acc1 = {};
    if (t > 0) {
      const unsigned short* hprev = ping + ((t - 1) & 1) * (BB * HH);
      const unsigned short* arow = hprev + (size_t)(wid * 16 + l15) * HH + kp;
#pragma unroll
      for (int ks = 0; ks < 32; ks += 2) {   // 2 accumulators to break dependent MFMA chain
        short8 a0 = *(const short8*)(arow + ks * 32);
        short8 b0 = *(const short8*)(brow + ks * 32);
        acc0 = __builtin_amdgcn_mfma_f32_16x16x32_bf16(a0, b0, acc0, 0, 0, 0);
        short8 a1 = *(const short8*)(arow + (ks + 1) * 32);
        short8 b1 = *(const short8*)(brow + (ks + 1) * 32);
        acc1 = __builtin_amdgcn_mfma_f32_16x16x32_bf16(a1, b1, acc1, 0, 0, 0);
      }
    }
    unsigned short* hcur = ping + (t & 1) * (BB * HH);
#pragma unroll
    for (int jj = 0; jj < 4; ++jj) {
      const int b = wid * 16 + (lane >> 4) * 4 + jj;   // C/D frag: col=lane&15, row=(lane>>4)*4+reg
      const size_t gidx = (size_t)(b * TT + t) * HH + col;
      const float pre = acc0[jj] + acc1[jj] + G[gidx];
      const float h = tanhf(pre);
      const unsigned short hb = f2bf(h);
      hcur[b * HH + col] = hb;
      if (h0strided) h0strided[gidx] = hb;
      if (outf) outf[gidx] = h;
      if (t == TT - 1) hT[b * HH + col] = h;
    }
    // ---- grid barrier (sense via monotonically increasing step value) ----
    __syncthreads();                       // compiler drains vmcnt before s_barrier
    if (tid == 0) {
      __threadfence();                     // release: flush to agent scope
      __hip_atomic_store(&flags[g * 256], (unsigned)(t + 1), __ATOMIC_RELEASE,
                         __HIP_MEMORY_SCOPE_AGENT);
    }
    if (wid == 0) {
      const unsigned tgt = (unsigned)(t + 1);
      while (1) {
        unsigned v = __hip_atomic_load(&flags[lane * 256], __ATOMIC_RELAXED,
                                       __HIP_MEMORY_SCOPE_AGENT);
        if (__all((int)(v >= tgt))) break;
        __builtin_amdgcn_s_sleep(1);
      }
    }
    __syncthreads();
    __threadfence();                       // acquire: invalidate stale cached h lines
  }
}

extern "C" void kernel_launch(void* const* d_in, const int* in_sizes, int n_in,
                              void* d_out, int out_size, void* d_ws, size_t ws_size,
                              hipStream_t stream) {
  const float* Xt  = (const float*)d_in[0];
  const float* Wih = (const float*)d_in[1];
  const float* bih = (const float*)d_in[2];
  const float* Whh = (const float*)d_in[3];
  const float* bhh = (const float*)d_in[4];
  float* out = (float*)d_out;                    // [B,T,H], reused as G scratch
  float* hT  = out + (size_t)BB * TT * HH;       // [L,B,H]

  char* ws = (char*)d_ws;
  unsigned short* wih_b  = (unsigned short*)(ws);                 // 4 MB  (L*H*H bf16)
  unsigned short* whh_b  = (unsigned short*)(ws + (4u << 20));    // 4 MB
  float*          bias01 = (float*)(ws + (8u << 20));             // 8 KB  (L*H fp32)
  unsigned short* h0buf  = (unsigned short*)(ws + (16u << 20));   // 128 MB (B*T*H bf16)
  unsigned short* ping   = (unsigned short*)(ws + (160u << 20));  // 512 KB [L][2][B*H]
  unsigned int*   flags  = (unsigned int*)(ws + (161u << 20));    // 128 KB

  if (ws_size < (162u << 20)) return;  // insufficient workspace -> loud validation failure

  hipMemsetAsync(flags, 0, 128 * 1024, stream);
  prep_kernel<<<8192, 256, 0, stream>>>(Wih, Whh, bih, bhh, wih_b, whh_b, bias01);

  // Phase A: G0 = Xt @ Wih0^T + (bih0+bhh0)  -> d_out scratch
  gemm_bias<false><<<4096, 256, 0, stream>>>(Xt, wih_b, bias01, out);

  // Phase B: layer-0 recurrence, writes bf16 H0 into ws
  {
    const float* G = out;
    const unsigned short* W = whh_b;
    unsigned short* pg = ping;
    unsigned short* h0s = h0buf;
    float* of = nullptr;
    float* ht = hT;
    unsigned int* fl = flags;
    void* args[] = {&G, &W, &pg, &h0s, &of, &ht, &fl};
    hipLaunchCooperativeKernel((void*)rec_layer, dim3(64), dim3(256), args, 0, stream);
  }

  // Phase C: G1 = H0 @ Wih1^T + (bih1+bhh1)  -> d_out scratch (G0 dead)
  gemm_bias<true><<<4096, 256, 0, stream>>>(h0buf, wih_b + (size_t)HH * HH, bias01 + HH, out);

  // Phase D: layer-1 recurrence, writes fp32 out in place + final hT
  {
    const float* G = out;
    const unsigned short* W = whh_b + (size_t)HH * HH;
    unsigned short* pg = ping + 2 * (size_t)BB * HH;
    unsigned short* h0s = nullptr;
    float* of = out;
    float* ht = hT + (size_t)BB * HH;
    unsigned int* fl = flags + (64u * 1024u / 4u);
    void* args[] = {&G, &W, &pg, &h0s, &of, &ht, &fl};
    hipLaunchCooperativeKernel((void*)rec_layer, dim3(64), dim3(256), args, 0, stream);
  }
}

// Round 2
// 14374.518 us; speedup vs baseline: 1.9354x; 1.9354x over previous
//
#include <hip/hip_runtime.h>
#include <hip/hip_bf16.h>
#include <stdint.h>

#define HH 1024
#define BB 64
#define TT 1024

typedef __attribute__((ext_vector_type(8))) short short8;
typedef __attribute__((ext_vector_type(4))) float f32x4;

__device__ __forceinline__ unsigned short f2bf(float f) {
  union { float f; unsigned u; } v; v.f = f;
  unsigned r = v.u + 0x7fffu + ((v.u >> 16) & 1u);
  return (unsigned short)(r >> 16);
}

// Convert weights to bf16 (RNE) and fold the two biases together.
__global__ void prep_kernel(const float* __restrict__ Wih, const float* __restrict__ Whh,
                            const float* __restrict__ bih, const float* __restrict__ bhh,
                            unsigned short* __restrict__ wih_b, unsigned short* __restrict__ whh_b,
                            float* __restrict__ bias01) {
  int i = blockIdx.x * 256 + threadIdx.x;   // grid sized exactly 2*H*H
  wih_b[i] = f2bf(Wih[i]);
  whh_b[i] = f2bf(Whh[i]);
  if (i < 2 * HH) bias01[i] = bih[i] + bhh[i];
}

// Row permutation between [b][t] and [t][b] orderings (B=64, T=1024, M=65536):
// r = t*64 + b  <->  perm(r) = b*1024 + t. Involution-like pair used for A-read / C-write.
__device__ __forceinline__ size_t rowperm(int r) {
  return ((size_t)(r & 63) << 10) | (size_t)(r >> 6);
}

// Bulk GEMM: Gout[crow(r), n] = sum_k A[arow(r),k] * W[n,k] + bias[n].
// A is fp32 (converted on the fly) or bf16. M = 65536, N = K = 1024.
// 128x128 tile, BK=32, 4 waves each computing 64x64 (4x4 of 16x16x32 MFMA).
template<bool ABF16, bool APERM, bool CPERM>
__global__ __launch_bounds__(256)
void gemm_bias(const void* __restrict__ Av, const unsigned short* __restrict__ Wb,
               const float* __restrict__ bias, float* __restrict__ Gout) {
  __shared__ unsigned short As[128 * 40];  // +8 bf16 pad: 80B stride -> 2-way bank alias (free)
  __shared__ unsigned short Bs[128 * 40];
  const int tn = blockIdx.x & 7;
  const int tm = blockIdx.x >> 3;
  const int tid = threadIdx.x;
  const int wid = tid >> 6, lane = tid & 63;
  const int wr = (wid >> 1) * 64, wc = (wid & 1) * 64;
  const int l15 = lane & 15, l4 = lane >> 4;
  f32x4 acc[4][4] = {};

  const float* Af = (const float*)Av;
  const unsigned short* Ab = (const unsigned short*)Av;
  const int sr = tid >> 2;          // 0..63
  const int sk = (tid & 3) * 8;     // 0,8,16,24

  for (int k0 = 0; k0 < HH; k0 += 32) {
    __syncthreads();
#pragma unroll
    for (int p = 0; p < 2; ++p) {
      const int row = p * 64 + sr;
      const int rg = tm * 128 + row;
      const size_t ar = APERM ? rowperm(rg) : (size_t)rg;
      if (ABF16) {
        const unsigned short* src = Ab + ar * HH + k0 + sk;
        *(short8*)&As[row * 40 + sk] = *(const short8*)src;
      } else {
        const float* src = Af + ar * HH + k0 + sk;
        float4 x = *(const float4*)src;
        float4 y = *(const float4*)(src + 4);
        short8 v;
        v[0] = (short)f2bf(x.x); v[1] = (short)f2bf(x.y);
        v[2] = (short)f2bf(x.z); v[3] = (short)f2bf(x.w);
        v[4] = (short)f2bf(y.x); v[5] = (short)f2bf(y.y);
        v[6] = (short)f2bf(y.z); v[7] = (short)f2bf(y.w);
        *(short8*)&As[row * 40 + sk] = v;
      }
      const unsigned short* wsrc = Wb + (size_t)(tn * 128 + row) * HH + k0 + sk;
      *(short8*)&Bs[row * 40 + sk] = *(const short8*)wsrc;
    }
    __syncthreads();
    short8 a[4], b[4];
#pragma unroll
    for (int i = 0; i < 4; ++i) a[i] = *(short8*)&As[(wr + i * 16 + l15) * 40 + l4 * 8];
#pragma unroll
    for (int j = 0; j < 4; ++j) b[j] = *(short8*)&Bs[(wc + j * 16 + l15) * 40 + l4 * 8];
#pragma unroll
    for (int i = 0; i < 4; ++i)
#pragma unroll
      for (int j = 0; j < 4; ++j)
        acc[i][j] = __builtin_amdgcn_mfma_f32_16x16x32_bf16(a[i], b[j], acc[i][j], 0, 0, 0);
  }
#pragma unroll
  for (int j = 0; j < 4; ++j) {
    const int gc = tn * 128 + wc + j * 16 + l15;
    const float bv = bias[gc];
#pragma unroll
    for (int i = 0; i < 4; ++i) {
#pragma unroll
      for (int jj = 0; jj < 4; ++jj) {
        const int gr = tm * 128 + wr + i * 16 + l4 * 4 + jj;
        const size_t orow = CPERM ? rowperm(gr) : (size_t)gr;
        Gout[orow * HH + gc] = acc[i][j][jj] + bv;
      }
    }
  }
}

// Persistent recurrent kernel (one layer). 64 WGs x 256 threads, cooperative.
// WG g owns output columns [g*16, g*16+16). Whh column-slice resident in LDS.
// Per step t: pre = G[t, :, cols] + h_{t-1} @ Whh_sliceT ; h = tanh(pre).
//
// Sync protocol (no buffer_wbl2 anywhere):
//   producer: hcur via write-through stores (sc0 sc1), per-wave vmcnt(0) drain,
//             __syncthreads, tid0 publishes flag with write-through dword store.
//   consumer: wave0 polls flags with bypass loads (sc0 sc1), then a single
//             acquire-only agent fence (buffer_inv, no writeback), __syncthreads.
// LAYER==0: G layout [t][b][h] (contiguous per step), writes bf16 h0 to h0s (same idx).
// LAYER==1: G layout [b][t][h], writes fp32 out in place over G (same element, same step).
template<int LAYER>
__global__ __launch_bounds__(256)
void rec_layer(const float* G,
               const unsigned short* __restrict__ Whh_b,
               unsigned short* __restrict__ ping,
               unsigned short* __restrict__ h0s,
               float* outf,
               float* __restrict__ hT,
               unsigned int* flags) {
  const int g = blockIdx.x;
  const int tid = threadIdx.x, wid = tid >> 6, lane = tid & 63;
  const int l15 = lane & 15, l4 = lane >> 4, kp = l4 * 8;
  __shared__ unsigned short Wl[16 * 1032];  // 16 cols x 1024 k, stride 1032 (2-way alias only)

  for (int idx = tid; idx < 16 * 64; idx += 256) {
    const int j = idx >> 6, kseg = (idx & 63) * 16;
    const short8* src = (const short8*)&Whh_b[(size_t)(g * 16 + j) * HH + kseg];
    *(short8*)&Wl[j * 1032 + kseg] = src[0];
    *(short8*)&Wl[j * 1032 + kseg + 8] = src[1];
  }
  __syncthreads();

  const int col = g * 16 + l15;
  const unsigned short* brow = (const unsigned short*)&Wl[l15 * 1032 + kp];
  const uint64_t myflag = (uint64_t)(flags + (size_t)g * 256);
  const uint64_t pollflag = (uint64_t)(flags + (size_t)lane * 256);

  // per-thread output rows b (4 of them) and their G indices
  int bidx[4];
#pragma unroll
  for (int jj = 0; jj < 4; ++jj) bidx[jj] = wid * 16 + l4 * 4 + jj;

  float gv[4], gn[4];
#pragma unroll
  for (int jj = 0; jj < 4; ++jj) {
    const size_t gi = (LAYER == 0) ? ((size_t)(0 * BB + bidx[jj])) * HH + col
                                   : ((size_t)(bidx[jj] * TT + 0)) * HH + col;
    gv[jj] = G[gi];
  }

  for (int t = 0; t < TT; ++t) {
    // prefetch G for t+1 early (immutable data -> safe to read across the barrier)
    if (t + 1 < TT) {
#pragma unroll
      for (int jj = 0; jj < 4; ++jj) {
        const size_t gi = (LAYER == 0) ? ((size_t)((t + 1) * BB + bidx[jj])) * HH + col
                                       : ((size_t)(bidx[jj] * TT + (t + 1))) * HH + col;
        gn[jj] = G[gi];
      }
    }

    f32x4 acc0 = {}, acc1 = {};
    if (t > 0) {
      const unsigned short* hprev = ping + ((t - 1) & 1) * (BB * HH);
      const unsigned short* arow = hprev + (size_t)(wid * 16 + l15) * HH + kp;
#pragma unroll
      for (int ks = 0; ks < 32; ks += 2) {   // 2 accumulators to break dependent MFMA chain
        short8 a0 = *(const short8*)(arow + ks * 32);
        short8 b0 = *(const short8*)(brow + ks * 32);
        acc0 = __builtin_amdgcn_mfma_f32_16x16x32_bf16(a0, b0, acc0, 0, 0, 0);
        short8 a1 = *(const short8*)(arow + (ks + 1) * 32);
        short8 b1 = *(const short8*)(brow + (ks + 1) * 32);
        acc1 = __builtin_amdgcn_mfma_f32_16x16x32_bf16(a1, b1, acc1, 0, 0, 0);
      }
    }

    unsigned short* hcur = ping + (t & 1) * (BB * HH);
#pragma unroll
    for (int jj = 0; jj < 4; ++jj) {
      const int b = bidx[jj];
      const size_t gidx = (LAYER == 0) ? ((size_t)(t * BB + b)) * HH + col
                                       : ((size_t)(b * TT + t)) * HH + col;
      const float pre = acc0[jj] + acc1[jj] + gv[jj];
      const float h = tanhf(pre);
      const unsigned short hb = f2bf(h);
      // write-through recurrent-state store (visible at coherence point, no wbl2 needed)
      {
        const uint64_t ha = (uint64_t)(hcur + (size_t)b * HH + col);
        asm volatile("global_store_short %0, %1, off sc0 sc1"
                     :: "v"(ha), "v"((unsigned)hb) : "memory");
      }
      if (LAYER == 0) h0s[gidx] = hb;      // normal store, flushed at kernel boundary
      else            outf[gidx] = h;      // in-place over G element just consumed
      if (t == TT - 1) hT[b * HH + col] = h;
    }

    // ---- grid barrier ----
    asm volatile("s_waitcnt vmcnt(0)" ::: "memory");  // drain this wave's WT stores
    __syncthreads();
    if (tid == 0) {
      const unsigned val = (unsigned)(t + 1);
      asm volatile("s_waitcnt vmcnt(0)\n\t"
                   "global_store_dword %0, %1, off sc0 sc1"
                   :: "v"(myflag), "v"(val) : "memory");
    }
    if (wid == 0) {
      const unsigned tgt = (unsigned)(t + 1);
      unsigned v;
      do {
        asm volatile("global_load_dword %0, %1, off sc0 sc1\n\t"
                     "s_waitcnt vmcnt(0)"
                     : "=v"(v) : "v"(pollflag) : "memory");
      } while (!__all((int)(v >= tgt)));
      __builtin_amdgcn_fence(__ATOMIC_ACQUIRE, "agent");  // buffer_inv only, no wbl2
    }
    __syncthreads();

#pragma unroll
    for (int jj = 0; jj < 4; ++jj) gv[jj] = gn[jj];
  }
}

extern "C" void kernel_launch(void* const* d_in, const int* in_sizes, int n_in,
                              void* d_out, int out_size, void* d_ws, size_t ws_size,
                              hipStream_t stream) {
  const float* Xt  = (const float*)d_in[0];
  const float* Wih = (const float*)d_in[1];
  const float* bih = (const float*)d_in[2];
  const float* Whh = (const float*)d_in[3];
  const float* bhh = (const float*)d_in[4];
  float* out = (float*)d_out;                    // [B,T,H], reused as G scratch
  float* hT  = out + (size_t)BB * TT * HH;       // [L,B,H]

  char* ws = (char*)d_ws;
  unsigned short* wih_b  = (unsigned short*)(ws);                 // 4 MB  (L*H*H bf16)
  unsigned short* whh_b  = (unsigned short*)(ws + (4u << 20));    // 4 MB
  float*          bias01 = (float*)(ws + (8u << 20));             // 8 KB  (L*H fp32)
  unsigned short* h0buf  = (unsigned short*)(ws + (16u << 20));   // 128 MB (B*T*H bf16, [t][b][h])
  unsigned short* ping   = (unsigned short*)(ws + (160u << 20));  // 512 KB [L][2][B*H]
  unsigned int*   flags  = (unsigned int*)(ws + (161u << 20));    // 128 KB

  if (ws_size < (162u << 20)) return;  // insufficient workspace -> loud validation failure

  hipMemsetAsync(flags, 0, 128 * 1024, stream);
  prep_kernel<<<8192, 256, 0, stream>>>(Wih, Whh, bih, bhh, wih_b, whh_b, bias01);

  // Phase A: G0[t][b][:] = Xt[b][t][:] @ Wih0^T + (bih0+bhh0)  -> d_out scratch
  gemm_bias<false, true, false><<<4096, 256, 0, stream>>>(Xt, wih_b, bias01, out);

  // Phase B: layer-0 recurrence, writes bf16 H0 ([t][b][h]) into ws
  {
    const float* G = out;
    const unsigned short* W = whh_b;
    unsigned short* pg = ping;
    unsigned short* h0s = h0buf;
    float* of = nullptr;
    float* ht = hT;
    unsigned int* fl = flags;
    void* args[] = {&G, &W, &pg, &h0s, &of, &ht, &fl};
    hipLaunchCooperativeKernel((void*)rec_layer<0>, dim3(64), dim3(256), args, 0, stream);
  }

  // Phase C: G1[b][t][:] = H0[t][b][:] @ Wih1^T + (bih1+bhh1)  -> d_out scratch (G0 dead)
  gemm_bias<true, false, true><<<4096, 256, 0, stream>>>(h0buf, wih_b + (size_t)HH * HH,
                                                         bias01 + HH, out);

  // Phase D: layer-1 recurrence, writes fp32 out in place + final hT
  {
    const float* G = out;
    const unsigned short* W = whh_b + (size_t)HH * HH;
    unsigned short* pg = ping + 2 * (size_t)BB * HH;
    unsigned short* h0s = h0buf;   // unused for LAYER==1
    float* of = out;
    float* ht = hT + (size_t)BB * HH;
    unsigned int* fl = flags + (64u * 1024u / 4u);
    void* args[] = {&G, &W, &pg, &h0s, &of, &ht, &fl};
    hipLaunchCooperativeKernel((void*)rec_layer<1>, dim3(64), dim3(256), args, 0, stream);
  }
}